// Round 11
// baseline (681.685 us; speedup 1.0000x reference)
//
#include <hip/hip_runtime.h>
#include <math.h>

// Problem constants (B=8, C=128, H=W=48 -> N=2304, E=6C=768), fp32 in/out.
constexpr int kB   = 8;
constexpr int kC   = 128;
constexpr int kN   = 2304;   // 48*48
constexpr int kE   = 768;
constexpr int kQKV = kC + kC + kE;  // 1024 fused projection rows

constexpr int TILE = 128;
constexpr int BK   = 32;
constexpr int TPAD = 132;  // fp32 path LDS row pad (words)
constexpr int KPAD = 40;   // bf16 path LDS row stride in ushort (80 B)

// Split-plane row widths (ushorts): row = [hi plane | lo plane]
constexpr int QROW = 2 * kN;  // 4608 u16 (9216 B)  for q/k/v/P rows
constexpr int EROW = 2 * kE;  // 1536 u16 (3072 B)  for wo/aout rows

#define SCALE 0.08838834764831845f  // 1/sqrt(128)

typedef float          f32x4 __attribute__((ext_vector_type(4)));
typedef short          s16x8 __attribute__((ext_vector_type(8)));
typedef unsigned short u16x8 __attribute__((ext_vector_type(8)));
typedef unsigned short u16x4 __attribute__((ext_vector_type(4)));

// ======================= fp32 vector-GEMM machinery =======================
// (audited; used by the qkv kernel's main loop)

__device__ __forceinline__ void load_direct(const float* __restrict__ g, int ld,
                                            int k0, int t0, float (*s)[TPAD]) {
  const int tid = threadIdx.x;
  const int c   = (tid & 31) * 4;
  const int r0  = tid >> 5;
#pragma unroll
  for (int rr = 0; rr < 4; ++rr) {
    const int k = r0 + rr * 8;
    const float4 v = *(const float4*)&g[(size_t)(k0 + k) * ld + t0 + c];
    *(float4*)&s[k][c] = v;
  }
}

__device__ __forceinline__ void load_trans(const float* __restrict__ g, int ld,
                                           int k0, int t0, float (*s)[TPAD]) {
  const int tid = threadIdx.x;
  const int kc  = (tid & 7) * 4;
  const int r0  = tid >> 3;
#pragma unroll
  for (int rr = 0; rr < 4; ++rr) {
    const int t = r0 + rr * 32;
    const float4 v = *(const float4*)&g[(size_t)(t0 + t) * ld + k0 + kc];
    s[kc + 0][t] = v.x;
    s[kc + 1][t] = v.y;
    s[kc + 2][t] = v.z;
    s[kc + 3][t] = v.w;
  }
}

__device__ __forceinline__ void mm_core(const float (*sA)[TPAD], const float (*sB)[TPAD],
                                        int ty, int tx, float acc[2][2][4][4]) {
#pragma unroll
  for (int kk = 0; kk < BK; ++kk) {
    const float4 a0 = *(const float4*)&sA[kk][ty * 4];
    const float4 a1 = *(const float4*)&sA[kk][64 + ty * 4];
    const float4 b0 = *(const float4*)&sB[kk][tx * 4];
    const float4 b1 = *(const float4*)&sB[kk][64 + tx * 4];
    const float a[2][4] = {{a0.x, a0.y, a0.z, a0.w}, {a1.x, a1.y, a1.z, a1.w}};
    const float b[2][4] = {{b0.x, b0.y, b0.z, b0.w}, {b1.x, b1.y, b1.z, b1.w}};
#pragma unroll
    for (int p = 0; p < 2; ++p)
#pragma unroll
      for (int q = 0; q < 2; ++q)
#pragma unroll
        for (int i = 0; i < 4; ++i)
#pragma unroll
          for (int j = 0; j < 4; ++j)
            acc[p][q][i][j] += a[p][i] * b[q][j];
  }
}

// ======================= split-bf16 MFMA machinery ========================
// Numerics (validated R10, absmax 1.95e-3): fp32 x = hi + lo + eps (~2^-17),
// D = Ah*Bh + Ah*Bl + Al*Bh via 3 chained MFMAs.
//
// NEW this round: every MFMA operand is PRE-SPLIT at its producer and stored
// as per-row planes [hi[W] | lo[W]] (u16). Consumers copy-stage; the split
// VALU work and its per-panel redundancy (6-18x) are gone.
//
// LDS tiles [t][k] u16, row stride KPAD=40 (80 B). Element (t,k) at column
// k ^ (((t>>2)&3)<<3) (validated). Fragments: lane elems e=0..7 hold
// k = 8*(lane>>4)+e (same map for A and B -> k-permutation invariant).
// D: col=lane&15, row=4*(lane>>4)+reg [m89, HW-validated R10].

__device__ __forceinline__ void split_bf16(float x, unsigned short& hi,
                                           unsigned short& lo) {
  const __bf16 h = (__bf16)x;
  const float  r = x - (float)h;   // exact
  const __bf16 l = (__bf16)r;
  hi = __builtin_bit_cast(unsigned short, h);
  lo = __builtin_bit_cast(unsigned short, l);
}

// Copy-stage a [TILE]x[BK] tile whose k-dim is CONTIGUOUS within each split
// row. base points at row t0's hi element k0; rstride = u16 row stride;
// loOff = u16 offset from hi[k] to lo[k] within a row.
__device__ __forceinline__ void stage_rows_copy(
    const unsigned short* __restrict__ base, size_t rstride, int loOff,
    unsigned short (*sHi)[KPAD], unsigned short (*sLo)[KPAD]) {
  const int tid = threadIdx.x;
  const int t   = tid >> 1;     // 0..127
  const int h   = tid & 1;      // which 16-k half
  const unsigned short* rp = base + (size_t)t * rstride + h * 16;
  const int sw = ((t >> 2) & 3) << 3;
  const u16x8 a0 = *(const u16x8*)(rp);
  const u16x8 a1 = *(const u16x8*)(rp + 8);
  const u16x8 b0 = *(const u16x8*)(rp + loOff);
  const u16x8 b1 = *(const u16x8*)(rp + loOff + 8);
  *(u16x8*)&sHi[t][(h * 16) ^ sw]     = a0;
  *(u16x8*)&sHi[t][(h * 16 + 8) ^ sw] = a1;
  *(u16x8*)&sLo[t][(h * 16) ^ sw]     = b0;
  *(u16x8*)&sLo[t][(h * 16 + 8) ^ sw] = b1;
}

// Copy-stage a [TILE]x[BK] tile whose k-dim runs ACROSS split rows (scores:
// k=c is the row index, t=n contiguous). base points at row k0's hi elem t0.
__device__ __forceinline__ void stage_cols_copy(
    const unsigned short* __restrict__ base,
    unsigned short (*sHi)[KPAD], unsigned short (*sLo)[KPAD]) {
  const int tid = threadIdx.x;
  const int c   = tid & 31;    // k row
  const int oct = tid >> 5;    // 0..7
  const unsigned short* rp = base + (size_t)c * QROW;
#pragma unroll
  for (int rep = 0; rep < 2; ++rep) {
    const int nb = oct * 8 + rep * 64;
    const u16x8 h8 = *(const u16x8*)(rp + nb);
    const u16x8 l8 = *(const u16x8*)(rp + kN + nb);
#pragma unroll
    for (int e = 0; e < 8; ++e) {
      const int t  = nb + e;
      const int kz = c ^ (((t >> 2) & 3) << 3);
      sHi[t][kz] = h8[e];
      sLo[t][kz] = l8[e];
    }
  }
}

__device__ __forceinline__ s16x8 frag8(const unsigned short (*s)[KPAD], int t, int g) {
  const int col = 8 * (g ^ ((t >> 2) & 3));
  return *(const s16x8*)&s[t][col];
}

__device__ __forceinline__ void mfma_core_split(
    const unsigned short (*aHi)[KPAD], const unsigned short (*aLo)[KPAD],
    const unsigned short (*bHi)[KPAD], const unsigned short (*bLo)[KPAD],
    int wr, int wc, int lane, f32x4 acc[4][4]) {
  const int g  = lane >> 4;
  const int tr = lane & 15;
  s16x8 bh[4], bl[4];
#pragma unroll
  for (int ni = 0; ni < 4; ++ni) {
    const int t = wc * 64 + ni * 16 + tr;
    bh[ni] = frag8(bHi, t, g);
    bl[ni] = frag8(bLo, t, g);
  }
#pragma unroll
  for (int mi = 0; mi < 4; ++mi) {
    const int t = wr * 64 + mi * 16 + tr;
    const s16x8 ah = frag8(aHi, t, g);
    const s16x8 al = frag8(aLo, t, g);
#pragma unroll
    for (int ni = 0; ni < 4; ++ni) {
      acc[mi][ni] = __builtin_amdgcn_mfma_f32_16x16x32_bf16(ah, bh[ni], acc[mi][ni], 0, 0, 0);
      acc[mi][ni] = __builtin_amdgcn_mfma_f32_16x16x32_bf16(ah, bl[ni], acc[mi][ni], 0, 0, 0);
      acc[mi][ni] = __builtin_amdgcn_mfma_f32_16x16x32_bf16(al, bh[ni], acc[mi][ni], 0, 0, 0);
    }
  }
}

// ---------------------------------------------------------------------------
// Kernel 0: split wo into planes wou[o] = [hi[768] | lo[768]].
// ---------------------------------------------------------------------------
__global__ __launch_bounds__(256) void wo_split_kernel(
    const float* __restrict__ wo, unsigned short* __restrict__ wou)
{
  const int o   = blockIdx.x;
  const int tid = threadIdx.x;
#pragma unroll
  for (int i = 0; i < 3; ++i) {
    const int e = tid + i * 256;
    unsigned short h, l;
    split_bf16(wo[(size_t)o * kE + e], h, l);
    wou[(size_t)o * EROW + e]       = h;
    wou[(size_t)o * EROW + kE + e]  = l;
  }
}

// ---------------------------------------------------------------------------
// Kernel 1 (fp32 compute, split output): fused QKV projection.
// Row (b,o) of qkvu = [hi[2304] | lo[2304]] of (Wcat.x + bias).
// ---------------------------------------------------------------------------
__global__ __launch_bounds__(256) void qkv_kernel(
    const float* __restrict__ x,
    const float* __restrict__ wq, const float* __restrict__ bq,
    const float* __restrict__ wk, const float* __restrict__ bk,
    const float* __restrict__ wv, const float* __restrict__ bv,
    unsigned short* __restrict__ qkvu)
{
  __shared__ float sA[BK][TPAD];
  __shared__ float sB[BK][TPAD];
  const int b   = blockIdx.z;
  const int o0  = blockIdx.y * TILE;
  const int n0  = blockIdx.x * TILE;
  const int tid = threadIdx.x;
  const int tx  = tid & 15, ty = tid >> 4;
  float acc[2][2][4][4] = {};
  const float* xb = x + (size_t)b * kC * kN;

  const float* wsrc;
  const float* bsrc;
  int orow0;
  if (o0 < kC)           { wsrc = wq; bsrc = bq; orow0 = o0; }
  else if (o0 < 2 * kC)  { wsrc = wk; bsrc = bk; orow0 = o0 - kC; }
  else                   { wsrc = wv; bsrc = bv; orow0 = o0 - 2 * kC; }

  for (int k0 = 0; k0 < kC; k0 += BK) {
    load_trans(wsrc + (size_t)orow0 * kC, kC, k0, 0, sA);
    load_direct(xb, kN, k0, n0, sB);
    __syncthreads();
    mm_core(sA, sB, ty, tx, acc);
    __syncthreads();
  }

#pragma unroll
  for (int p = 0; p < 2; ++p)
#pragma unroll
    for (int i = 0; i < 4; ++i) {
      const int t    = p * 64 + ty * 4 + i;
      const int o    = o0 + t;
      const float bias = bsrc[orow0 + t];
      unsigned short* rowp =
          qkvu + ((size_t)b * kQKV + o) * QROW + n0;
#pragma unroll
      for (int q = 0; q < 2; ++q) {
        u16x4 h4, l4;
#pragma unroll
        for (int j = 0; j < 4; ++j) {
          unsigned short h, l;
          split_bf16(acc[p][q][i][j] + bias, h, l);
          h4[j] = h; l4[j] = l;
        }
        const int idx = q * 64 + tx * 4;
        *(u16x4*)&rowp[idx]      = h4;
        *(u16x4*)&rowp[kN + idx] = l4;
      }
    }
}

// ---------------------------------------------------------------------------
// Kernel 2 (MFMA, copy-staged): scores_slab[z][n][m] fp32 = SCALE * q.k
// for batch b0+z. K = c = 128.
// ---------------------------------------------------------------------------
__global__ __launch_bounds__(256) void scores_mfma_kernel(
    const unsigned short* __restrict__ qkvu, float* __restrict__ scores_slab,
    int b0)
{
  __shared__ unsigned short sAh[TILE][KPAD], sAl[TILE][KPAD];
  __shared__ unsigned short sBh[TILE][KPAD], sBl[TILE][KPAD];
  const int bz   = blockIdx.z;
  const int b    = b0 + bz;
  const int n0   = blockIdx.y * TILE;
  const int m0   = blockIdx.x * TILE;
  const int tid  = threadIdx.x;
  const int lane = tid & 63;
  const int wid  = tid >> 6;
  const int wr   = wid >> 1, wc = wid & 1;

  f32x4 acc[4][4];
#pragma unroll
  for (int mi = 0; mi < 4; ++mi)
#pragma unroll
    for (int ni = 0; ni < 4; ++ni) acc[mi][ni] = (f32x4)(0.0f);

  for (int k0 = 0; k0 < kC; k0 += BK) {
    stage_cols_copy(qkvu + ((size_t)b * kQKV + k0) * QROW + n0, sAh, sAl);
    stage_cols_copy(qkvu + ((size_t)b * kQKV + kC + k0) * QROW + m0, sBh, sBl);
    __syncthreads();
    mfma_core_split(sAh, sAl, sBh, sBl, wr, wc, lane, acc);
    __syncthreads();
  }

  float* sb = scores_slab + (size_t)bz * kN * kN;
  const int g = lane >> 4, c16 = lane & 15;
#pragma unroll
  for (int mi = 0; mi < 4; ++mi)
#pragma unroll
    for (int ni = 0; ni < 4; ++ni) {
      const int n = n0 + wr * 64 + mi * 16 + 4 * g;
      const int m = m0 + wc * 64 + ni * 16 + c16;
#pragma unroll
      for (int j = 0; j < 4; ++j)
        sb[(size_t)(n + j) * kN + m] = acc[mi][ni][j] * SCALE;
    }
}

// ---------------------------------------------------------------------------
// Kernel 3: row softmax; reads its fp32 row, writes the SAME row back as
// split planes [hi[2304] | lo[2304]] u16 (exactly overlays the fp32 row;
// all reads precede the reduction barrier -> in-place is race-free).
// ---------------------------------------------------------------------------
__global__ __launch_bounds__(256) void softmax_kernel(float* __restrict__ scores)
{
  const size_t row = blockIdx.x;
  float* p = scores + row * kN;
  const int tid = threadIdx.x;
  float v[9];
  float m = -3.0e38f;
#pragma unroll
  for (int i = 0; i < 9; ++i) {
    v[i] = p[tid + i * 256];
    m = fmaxf(m, v[i]);
  }
#pragma unroll
  for (int off = 32; off >= 1; off >>= 1) m = fmaxf(m, __shfl_down(m, off));
  __shared__ float redm[4], reds[4];
  if ((tid & 63) == 0) redm[tid >> 6] = m;
  __syncthreads();                      // also orders all row reads before writes
  m = fmaxf(fmaxf(redm[0], redm[1]), fmaxf(redm[2], redm[3]));
  float s = 0.f;
#pragma unroll
  for (int i = 0; i < 9; ++i) {
    v[i] = expf(v[i] - m);
    s += v[i];
  }
#pragma unroll
  for (int off = 32; off >= 1; off >>= 1) s += __shfl_down(s, off);
  if ((tid & 63) == 0) reds[tid >> 6] = s;
  __syncthreads();
  s = (reds[0] + reds[1]) + (reds[2] + reds[3]);
  const float inv = 1.f / s;
  unsigned short* pu = (unsigned short*)p;
#pragma unroll
  for (int i = 0; i < 9; ++i) {
    const int idx = tid + i * 256;
    unsigned short h, l;
    split_bf16(v[i] * inv, h, l);
    pu[idx]      = h;
    pu[kN + idx] = l;
  }
}

// ---------------------------------------------------------------------------
// Kernel 4 (MFMA, copy-staged): aout[b0+z][n] (split planes) = P . V.
// K = m = 2304. A from P planes (slab rows), B from v planes (qkvu rows).
// ---------------------------------------------------------------------------
__global__ __launch_bounds__(256) void av_mfma_kernel(
    const unsigned short* __restrict__ pslab,
    const unsigned short* __restrict__ qkvu,
    unsigned short* __restrict__ aoutu, int b0)
{
  __shared__ unsigned short sAh[TILE][KPAD], sAl[TILE][KPAD];
  __shared__ unsigned short sBh[TILE][KPAD], sBl[TILE][KPAD];
  const int bz   = blockIdx.z;
  const int b    = b0 + bz;
  const int n0   = blockIdx.y * TILE;
  const int e0   = blockIdx.x * TILE;
  const int tid  = threadIdx.x;
  const int lane = tid & 63;
  const int wid  = tid >> 6;
  const int wr   = wid >> 1, wc = wid & 1;

  f32x4 acc[4][4];
#pragma unroll
  for (int mi = 0; mi < 4; ++mi)
#pragma unroll
    for (int ni = 0; ni < 4; ++ni) acc[mi][ni] = (f32x4)(0.0f);

  const unsigned short* pbase = pslab + ((size_t)bz * kN + n0) * QROW;
  const unsigned short* vbase = qkvu + ((size_t)b * kQKV + 2 * kC + e0) * QROW;

  for (int k0 = 0; k0 < kN; k0 += BK) {
    stage_rows_copy(pbase + k0, QROW, kN, sAh, sAl);
    stage_rows_copy(vbase + k0, QROW, kN, sBh, sBl);
    __syncthreads();
    mfma_core_split(sAh, sAl, sBh, sBl, wr, wc, lane, acc);
    __syncthreads();
  }

  const int g = lane >> 4, c16 = lane & 15;
#pragma unroll
  for (int mi = 0; mi < 4; ++mi)
#pragma unroll
    for (int ni = 0; ni < 4; ++ni) {
      const int n = n0 + wr * 64 + mi * 16 + 4 * g;
      const int e = e0 + wc * 64 + ni * 16 + c16;
#pragma unroll
      for (int j = 0; j < 4; ++j) {
        unsigned short h, l;
        split_bf16(acc[mi][ni][j], h, l);
        unsigned short* rp = aoutu + ((size_t)b * kN + n + j) * EROW;
        rp[e]      = h;
        rp[kE + e] = l;
      }
    }
}

// ---------------------------------------------------------------------------
// Kernel 5 (MFMA, copy-staged): out[b][o][n] fp32 = wo . aout + bo.
// K = e = 768. A from wo planes, B from aout planes.
// ---------------------------------------------------------------------------
__global__ __launch_bounds__(256) void proj_mfma_kernel(
    const unsigned short* __restrict__ wou, const float* __restrict__ bo,
    const unsigned short* __restrict__ aoutu, float* __restrict__ out)
{
  __shared__ unsigned short sAh[TILE][KPAD], sAl[TILE][KPAD];
  __shared__ unsigned short sBh[TILE][KPAD], sBl[TILE][KPAD];
  const int b    = blockIdx.z;
  const int o0   = blockIdx.y * TILE;
  const int n0   = blockIdx.x * TILE;
  const int tid  = threadIdx.x;
  const int lane = tid & 63;
  const int wid  = tid >> 6;
  const int wr   = wid >> 1, wc = wid & 1;

  f32x4 acc[4][4];
#pragma unroll
  for (int mi = 0; mi < 4; ++mi)
#pragma unroll
    for (int ni = 0; ni < 4; ++ni) acc[mi][ni] = (f32x4)(0.0f);

  const unsigned short* abase = wou + (size_t)o0 * EROW;
  const unsigned short* bbase = aoutu + ((size_t)b * kN + n0) * EROW;

  for (int k0 = 0; k0 < kE; k0 += BK) {
    stage_rows_copy(abase + k0, EROW, kE, sAh, sAl);
    stage_rows_copy(bbase + k0, EROW, kE, sBh, sBl);
    __syncthreads();
    mfma_core_split(sAh, sAl, sBh, sBl, wr, wc, lane, acc);
    __syncthreads();
  }

  const int g = lane >> 4, c16 = lane & 15;
#pragma unroll
  for (int mi = 0; mi < 4; ++mi)
#pragma unroll
    for (int j = 0; j < 4; ++j) {
      const int o = o0 + wr * 64 + mi * 16 + 4 * g + j;
      const float bias = bo[o];
#pragma unroll
      for (int ni = 0; ni < 4; ++ni) {
        const int n = n0 + wc * 64 + ni * 16 + c16;
        out[((size_t)b * kE + o) * kN + n] = acc[mi][ni][j] + bias;
      }
    }
}

// ---------------------------------------------------------------------------
extern "C" void kernel_launch(void* const* d_in, const int* in_sizes, int n_in,
                              void* d_out, int out_size, void* d_ws, size_t ws_size,
                              hipStream_t stream) {
  const float* x  = (const float*)d_in[0];
  const float* wq = (const float*)d_in[1];
  const float* bq = (const float*)d_in[2];
  const float* wk = (const float*)d_in[3];
  const float* bk = (const float*)d_in[4];
  const float* wv = (const float*)d_in[5];
  const float* bv = (const float*)d_in[6];
  const float* wo = (const float*)d_in[7];
  const float* bo = (const float*)d_in[8];
  float* out = (float*)d_out;

  // Workspace (bytes): qkv planes 75.5 MB | scores/P slab G*21.2 MB |
  // aout planes 56.6 MB | wo planes 2.25 MB.
  const size_t qkvB  = (size_t)kB * kQKV * QROW * 2;   // 75.5 MB
  const size_t slab1 = (size_t)kN * kN * 4;            // 21.2 MB / batch
  const size_t aoutB = (size_t)kB * kN * EROW * 2;     // 56.6 MB
  const size_t woB   = (size_t)kE * EROW * 2;          // 2.25 MB
  const size_t baseB = qkvB + aoutB + woB;
  int G = 1;
  for (int g = 8; g >= 2; --g)
    if (ws_size >= baseB + (size_t)g * slab1) { G = g; break; }

  char* wsb = (char*)d_ws;
  unsigned short* qkvu  = (unsigned short*)wsb;
  float*          sslab = (float*)(wsb + qkvB);
  unsigned short* aoutu = (unsigned short*)(wsb + qkvB + (size_t)G * slab1);
  unsigned short* wou   = (unsigned short*)(wsb + qkvB + (size_t)G * slab1 + aoutB);

  dim3 blk(256);
  wo_split_kernel<<<dim3(kE), blk, 0, stream>>>(wo, wou);
  qkv_kernel<<<dim3(kN / TILE, kQKV / TILE, kB), blk, 0, stream>>>(
      x, wq, bq, wk, bk, wv, bv, qkvu);
  for (int b0 = 0; b0 < kB; b0 += G) {
    const int zz = (kB - b0) < G ? (kB - b0) : G;
    scores_mfma_kernel<<<dim3(kN / TILE, kN / TILE, zz), blk, 0, stream>>>(
        qkvu, sslab, b0);
    softmax_kernel<<<dim3(zz * kN), blk, 0, stream>>>(sslab);
    av_mfma_kernel<<<dim3(kE / TILE, kN / TILE, zz), blk, 0, stream>>>(
        (const unsigned short*)sslab, qkvu, aoutu, b0);
  }
  proj_mfma_kernel<<<dim3(kN / TILE, kE / TILE, kB), blk, 0, stream>>>(
      wou, bo, aoutu, out);
}